// Round 1
// baseline (815.264 us; speedup 1.0000x reference)
//
#include <hip/hip_runtime.h>
#include <cstdint>

// ---------------------------------------------------------------------------
// 3-layer GAT (PyG GATConv semantics) on MI355X, fp32 throughout.
// Pipeline per launch:
//   CSR build by dst (histogram -> 1-block scan -> atomic scatter)
//   per layer: GEMM (h = X@W) -> alpha dots -> segment max/denom -> aggregate
// Workspace layout (~110 MB, all initialized before read every launch).
// ---------------------------------------------------------------------------

__global__ __launch_bounds__(256) void count_kernel(const int* __restrict__ ei,
                                                    int E, int N,
                                                    int* __restrict__ deg) {
  int g = blockIdx.x * 256 + threadIdx.x;
  if (g >= E + N) return;
  int dst = (g < E) ? ei[E + g] : (g - E);  // self-loop tail
  atomicAdd(&deg[dst], 1);
}

__global__ __launch_bounds__(1024) void scan_kernel(const int* __restrict__ deg,
                                                    int* __restrict__ row_off,
                                                    int* __restrict__ cursor,
                                                    int N) {
  __shared__ int buf[1024];
  __shared__ int carry;
  if (threadIdx.x == 0) carry = 0;
  __syncthreads();
  for (int base = 0; base < N; base += 1024) {
    int i = base + threadIdx.x;
    int v = (i < N) ? deg[i] : 0;
    buf[threadIdx.x] = v;
    __syncthreads();
    for (int off = 1; off < 1024; off <<= 1) {
      int t = (threadIdx.x >= off) ? buf[threadIdx.x - off] : 0;
      __syncthreads();
      buf[threadIdx.x] += t;
      __syncthreads();
    }
    if (i < N) {
      int ro = carry + buf[threadIdx.x] - v;  // exclusive
      row_off[i] = ro;
      cursor[i] = ro;
    }
    __syncthreads();
    if (threadIdx.x == 1023) carry += buf[1023];
    __syncthreads();
  }
  if (threadIdx.x == 0) row_off[N] = carry;
}

__global__ __launch_bounds__(256) void scatter_kernel(const int* __restrict__ ei,
                                                      int E, int N,
                                                      int* __restrict__ cursor,
                                                      int* __restrict__ esrc) {
  int g = blockIdx.x * 256 + threadIdx.x;
  if (g >= E + N) return;
  int src, dst;
  if (g < E) { src = ei[g]; dst = ei[E + g]; }
  else       { src = g - E; dst = src; }
  int pos = atomicAdd(&cursor[dst], 1);
  esrc[pos] = src;
}

// Tiled fp32 GEMM: C[M,Ncol] = A[M,K] @ B[K,Ncol]. 64x64 tile, 256 thr, 4x4/thr.
__global__ __launch_bounds__(256) void gemm_kernel(const float* __restrict__ A,
                                                   const float* __restrict__ B,
                                                   float* __restrict__ C,
                                                   int M, int K, int Ncol) {
  __shared__ float As[16][68];
  __shared__ float Bs[16][68];
  int tid = threadIdx.x;
  int row0 = blockIdx.x * 64, col0 = blockIdx.y * 64;
  int ty = tid >> 4, tx = tid & 15;
  int am = tid >> 2, ak = (tid & 3) << 2;
  int arow = row0 + am; if (arow > M - 1) arow = M - 1;
  int bk = tid >> 4, bn = (tid & 15) << 2;
  float acc[4][4] = {{0.f}};
  for (int kk = 0; kk < K; kk += 16) {
    float4 av = *reinterpret_cast<const float4*>(A + (size_t)arow * K + kk + ak);
    float4 bv = *reinterpret_cast<const float4*>(B + (size_t)(kk + bk) * Ncol + col0 + bn);
    As[ak + 0][am] = av.x;
    As[ak + 1][am] = av.y;
    As[ak + 2][am] = av.z;
    As[ak + 3][am] = av.w;
    *reinterpret_cast<float4*>(&Bs[bk][bn]) = bv;
    __syncthreads();
#pragma unroll
    for (int k = 0; k < 16; ++k) {
      float4 a = *reinterpret_cast<const float4*>(&As[k][ty << 2]);
      float4 b = *reinterpret_cast<const float4*>(&Bs[k][tx << 2]);
      float aa[4] = {a.x, a.y, a.z, a.w};
      float bb[4] = {b.x, b.y, b.z, b.w};
#pragma unroll
      for (int i = 0; i < 4; ++i)
#pragma unroll
        for (int j = 0; j < 4; ++j)
          acc[i][j] = fmaf(aa[i], bb[j], acc[i][j]);
    }
    __syncthreads();
  }
#pragma unroll
  for (int i = 0; i < 4; ++i) {
    int r = row0 + (ty << 2) + i;
    if (r < M) {
      float4 v = make_float4(acc[i][0], acc[i][1], acc[i][2], acc[i][3]);
      *reinterpret_cast<float4*>(C + (size_t)r * Ncol + col0 + (tx << 2)) = v;
    }
  }
}

// alpha_src/alpha_dst: wave per (node,head); lane = channel (C=64 = wave).
__global__ __launch_bounds__(256) void alpha_kernel(const float* __restrict__ Hf,
                                                    const float* __restrict__ a_src,
                                                    const float* __restrict__ a_dst,
                                                    float* __restrict__ asrc,
                                                    float* __restrict__ adst,
                                                    int N, int H) {
  int wave = threadIdx.x >> 6, lane = threadIdx.x & 63;
  int task = blockIdx.x * 4 + wave;
  if (task >= N * H) return;
  int n = task / H, h = task - n * H;
  float hv = Hf[(size_t)n * (H * 64) + h * 64 + lane];
  float vs = hv * a_src[h * 64 + lane];
  float vd = hv * a_dst[h * 64 + lane];
  for (int off = 32; off; off >>= 1) {
    vs += __shfl_xor(vs, off);
    vd += __shfl_xor(vd, off);
  }
  if (lane == 0) { asrc[task] = vs; adst[task] = vd; }
}

// Segment softmax stats: wave per dst; two passes over its edges (max, sumexp).
template <int H>
__global__ __launch_bounds__(256) void seg_softmax_stats(
    const int* __restrict__ row_off, const int* __restrict__ esrc,
    const float* __restrict__ asrc, const float* __restrict__ adst,
    float* __restrict__ mOut, float* __restrict__ rdenOut, int N) {
  int wave = threadIdx.x >> 6, lane = threadIdx.x & 63;
  int dst = blockIdx.x * 4 + wave;
  if (dst >= N) return;
  int r0 = row_off[dst], r1 = row_off[dst + 1];
  float ad[H];
#pragma unroll
  for (int h = 0; h < H; ++h) ad[h] = adst[dst * H + h];
  float mh[H];
#pragma unroll
  for (int h = 0; h < H; ++h) mh[h] = -1e30f;
  for (int j = r0 + lane; j < r1; j += 64) {
    int s = esrc[j];
#pragma unroll
    for (int h = 0; h < H; ++h) {
      float e = asrc[s * H + h] + ad[h];
      e = e > 0.f ? e : 0.2f * e;
      mh[h] = fmaxf(mh[h], e);
    }
  }
#pragma unroll
  for (int h = 0; h < H; ++h)
    for (int off = 32; off; off >>= 1) mh[h] = fmaxf(mh[h], __shfl_xor(mh[h], off));
  float sh[H];
#pragma unroll
  for (int h = 0; h < H; ++h) sh[h] = 0.f;
  for (int j = r0 + lane; j < r1; j += 64) {
    int s = esrc[j];
#pragma unroll
    for (int h = 0; h < H; ++h) {
      float e = asrc[s * H + h] + ad[h];
      e = e > 0.f ? e : 0.2f * e;
      sh[h] += expf(e - mh[h]);
    }
  }
#pragma unroll
  for (int h = 0; h < H; ++h) {
    for (int off = 32; off; off >>= 1) sh[h] += __shfl_xor(sh[h], off);
    if (lane == 0) {
      mOut[dst * H + h] = mh[h];
      rdenOut[dst * H + h] = 1.f / sh[h];
    }
  }
}

// Aggregation: block per dst. Stage per-edge softmax weights in LDS, then each
// thread (h,c) accumulates sum_j w[j,h] * hfeat[src_j, h*64+c]. Coalesced 1KB
// row gathers. Epilogue: +bias (+ELU for hidden layers).
template <int H, bool ELU>
__global__ __launch_bounds__(H * 64) void seg_aggregate(
    const float* __restrict__ hfeat, const int* __restrict__ row_off,
    const int* __restrict__ esrc, const float* __restrict__ asrc,
    const float* __restrict__ adst, const float* __restrict__ mIn,
    const float* __restrict__ rden, const float* __restrict__ bias,
    float* __restrict__ out, int N) {
  __shared__ int s_src[64];
  __shared__ float s_w[64][H];
  int dst = blockIdx.x;
  int t = threadIdx.x;
  int h = t >> 6;
  int r0 = row_off[dst], deg = row_off[dst + 1] - r0;
  float acc = 0.f;
  for (int base = 0; base < deg; base += 64) {
    int cnt = min(64, deg - base);
    __syncthreads();
    int j = t / H, hh = t - j * H;
    if (j < cnt) {
      int s = esrc[r0 + base + j];
      if (hh == 0) s_src[j] = s;
      float e = asrc[s * H + hh] + adst[dst * H + hh];
      e = e > 0.f ? e : 0.2f * e;
      s_w[j][hh] = expf(e - mIn[dst * H + hh]) * rden[dst * H + hh];
    }
    __syncthreads();
    for (int j2 = 0; j2 < cnt; ++j2)
      acc += s_w[j2][h] * hfeat[(size_t)s_src[j2] * (H * 64) + t];
  }
  float v = acc + bias[t];
  if (ELU) v = v > 0.f ? v : expm1f(v);
  out[(size_t)dst * (H * 64) + t] = v;
}

extern "C" void kernel_launch(void* const* d_in, const int* in_sizes, int n_in,
                              void* d_out, int out_size, void* d_ws, size_t ws_size,
                              hipStream_t stream) {
  const float* x   = (const float*)d_in[0];
  const int*   ei  = (const int*)d_in[1];
  const float* W1  = (const float*)d_in[2];
  const float* as1 = (const float*)d_in[3];
  const float* ad1 = (const float*)d_in[4];
  const float* b1  = (const float*)d_in[5];
  const float* W2  = (const float*)d_in[6];
  const float* as2 = (const float*)d_in[7];
  const float* ad2 = (const float*)d_in[8];
  const float* b2  = (const float*)d_in[9];
  const float* W3  = (const float*)d_in[10];
  const float* as3 = (const float*)d_in[11];
  const float* ad3 = (const float*)d_in[12];
  const float* b3  = (const float*)d_in[13];
  float* out = (float*)d_out;

  const int Fin = 128, H = 4, C = 64, HC = H * C;  // 256
  const int N = in_sizes[0] / Fin;
  const int E = in_sizes[1] / 2;
  const int ET = E + N;

  // workspace layout (floats unless noted)
  float* T    = (float*)d_ws;                 // [N, 256] gemm out
  float* F    = T + (size_t)N * HC;           // [N, 256] layer features
  float* asrc = F + (size_t)N * HC;           // [N, H]
  float* adst = asrc + (size_t)N * H;         // [N, H]
  float* mbuf = adst + (size_t)N * H;         // [N, H]
  float* rden = mbuf + (size_t)N * H;         // [N, H]
  int* deg     = (int*)(rden + (size_t)N * H);
  int* row_off = deg + N;
  int* cursor  = row_off + (N + 1);
  int* esrc    = cursor + N;                  // [E + N]

  // ---- CSR by destination (graph is identical for all 3 layers) ----
  hipMemsetAsync(deg, 0, N * sizeof(int), stream);
  count_kernel<<<(ET + 255) / 256, 256, 0, stream>>>(ei, E, N, deg);
  scan_kernel<<<1, 1024, 0, stream>>>(deg, row_off, cursor, N);
  scatter_kernel<<<(ET + 255) / 256, 256, 0, stream>>>(ei, E, N, cursor, esrc);

  // ---- Layer 1: 128 -> 4x64 (concat) + ELU ----
  gemm_kernel<<<dim3((N + 63) / 64, HC / 64), 256, 0, stream>>>(x, W1, T, N, Fin, HC);
  alpha_kernel<<<(N * H + 3) / 4, 256, 0, stream>>>(T, as1, ad1, asrc, adst, N, H);
  seg_softmax_stats<4><<<(N + 3) / 4, 256, 0, stream>>>(row_off, esrc, asrc, adst, mbuf, rden, N);
  seg_aggregate<4, true><<<N, 256, 0, stream>>>(T, row_off, esrc, asrc, adst, mbuf, rden, b1, F, N);

  // ---- Layer 2: 256 -> 4x64 (concat) + ELU ----
  gemm_kernel<<<dim3((N + 63) / 64, HC / 64), 256, 0, stream>>>(F, W2, T, N, HC, HC);
  alpha_kernel<<<(N * H + 3) / 4, 256, 0, stream>>>(T, as2, ad2, asrc, adst, N, H);
  seg_softmax_stats<4><<<(N + 3) / 4, 256, 0, stream>>>(row_off, esrc, asrc, adst, mbuf, rden, N);
  seg_aggregate<4, true><<<N, 256, 0, stream>>>(T, row_off, esrc, asrc, adst, mbuf, rden, b2, F, N);

  // ---- Layer 3: 256 -> 1x64 (mean over 1 head == identity) ----
  gemm_kernel<<<dim3((N + 63) / 64, C / 64), 256, 0, stream>>>(F, W3, T, N, HC, C);
  alpha_kernel<<<(N * 1 + 3) / 4, 256, 0, stream>>>(T, as3, ad3, asrc, adst, N, 1);
  seg_softmax_stats<1><<<(N + 3) / 4, 256, 0, stream>>>(row_off, esrc, asrc, adst, mbuf, rden, N);
  seg_aggregate<1, false><<<N, 64, 0, stream>>>(T, row_off, esrc, asrc, adst, mbuf, rden, b3, out, N);
}

// Round 2
// 675.780 us; speedup vs baseline: 1.2064x; 1.2064x over previous
//
#include <hip/hip_runtime.h>
#include <cstdint>

// ---------------------------------------------------------------------------
// 3-layer GAT (PyG GATConv semantics) on MI355X, fp32 throughout.
//   CSR build by dst (histogram -> 3-phase parallel scan -> atomic scatter)
//   per layer: GEMM (128x128 tile) -> alpha dots -> online-softmax aggregate
// ---------------------------------------------------------------------------

__global__ __launch_bounds__(256) void count_kernel(const int* __restrict__ ei,
                                                    int E, int N,
                                                    int* __restrict__ deg) {
  int g = blockIdx.x * 256 + threadIdx.x;
  if (g >= E + N) return;
  int dst = (g < E) ? ei[E + g] : (g - E);  // self-loop tail
  atomicAdd(&deg[dst], 1);
}

// Phase A: per-block (1024 elems) reduction of deg.
__global__ __launch_bounds__(256) void deg_block_reduce(const int* __restrict__ deg,
                                                        int* __restrict__ bsum, int N) {
  __shared__ int red[4];
  int b = blockIdx.x;
  int v = 0;
#pragma unroll
  for (int s = 0; s < 4; ++s) {
    int idx = b * 1024 + s * 256 + threadIdx.x;
    if (idx < N) v += deg[idx];
  }
  for (int off = 32; off; off >>= 1) v += __shfl_down(v, off);
  if ((threadIdx.x & 63) == 0) red[threadIdx.x >> 6] = v;
  __syncthreads();
  if (threadIdx.x == 0) bsum[b] = red[0] + red[1] + red[2] + red[3];
}

// Phase B: single block exclusive scan of NB block sums (NB <= 1024).
__global__ __launch_bounds__(1024) void small_scan(const int* __restrict__ bsum,
                                                   int* __restrict__ bpre, int NB) {
  __shared__ int buf[1024];
  int v = (threadIdx.x < NB) ? bsum[threadIdx.x] : 0;
  buf[threadIdx.x] = v;
  __syncthreads();
  for (int off = 1; off < 1024; off <<= 1) {
    int tv = (threadIdx.x >= off) ? buf[threadIdx.x - off] : 0;
    __syncthreads();
    buf[threadIdx.x] += tv;
    __syncthreads();
  }
  if (threadIdx.x < NB) bpre[threadIdx.x] = buf[threadIdx.x] - v;
}

// Phase C: per-block local scan + block prefix -> row_off, cursor.
__global__ __launch_bounds__(1024) void scan_final(const int* __restrict__ deg,
                                                   const int* __restrict__ bpre,
                                                   int* __restrict__ row_off,
                                                   int* __restrict__ cursor,
                                                   int N, int total) {
  __shared__ int buf[1024];
  int b = blockIdx.x;
  int i = b * 1024 + threadIdx.x;
  int v = (i < N) ? deg[i] : 0;
  buf[threadIdx.x] = v;
  __syncthreads();
  for (int off = 1; off < 1024; off <<= 1) {
    int tv = (threadIdx.x >= off) ? buf[threadIdx.x - off] : 0;
    __syncthreads();
    buf[threadIdx.x] += tv;
    __syncthreads();
  }
  if (i < N) {
    int ro = bpre[b] + buf[threadIdx.x] - v;  // exclusive
    row_off[i] = ro;
    cursor[i] = ro;
  }
  if (i == 0) row_off[N] = total;
}

__global__ __launch_bounds__(256) void scatter_kernel(const int* __restrict__ ei,
                                                      int E, int N,
                                                      int* __restrict__ cursor,
                                                      int* __restrict__ esrc) {
  int g = blockIdx.x * 256 + threadIdx.x;
  if (g >= E + N) return;
  int src, dst;
  if (g < E) { src = ei[g]; dst = ei[E + g]; }
  else       { src = g - E; dst = src; }
  int pos = atomicAdd(&cursor[dst], 1);
  esrc[pos] = src;
}

// fp32 GEMM: C[M,Ncol] = A[M,K] @ B[K,Ncol]. BM=128 x BN tile, 256 thr,
// per-thread 8 x (BN/16). K-step 16.
template <int BN>
__global__ __launch_bounds__(256) void gemm_big(const float* __restrict__ A,
                                                const float* __restrict__ B,
                                                float* __restrict__ C,
                                                int M, int K, int Ncol) {
  constexpr int TN = BN / 16;
  __shared__ float As[16][132];
  __shared__ float Bs[16][BN + 4];
  int tid = threadIdx.x;
  int row0 = blockIdx.x * 128, col0 = blockIdx.y * BN;
  int ty = tid >> 4, tx = tid & 15;
  int ar = tid >> 1, ak = (tid & 1) << 3;
  int arow = min(row0 + ar, M - 1);
  float acc[8][TN] = {};
  for (int kk = 0; kk < K; kk += 16) {
    const float* Ap = A + (size_t)arow * K + kk + ak;
    float4 a0 = *reinterpret_cast<const float4*>(Ap);
    float4 a1 = *reinterpret_cast<const float4*>(Ap + 4);
    As[ak + 0][ar] = a0.x; As[ak + 1][ar] = a0.y;
    As[ak + 2][ar] = a0.z; As[ak + 3][ar] = a0.w;
    As[ak + 4][ar] = a1.x; As[ak + 5][ar] = a1.y;
    As[ak + 6][ar] = a1.z; As[ak + 7][ar] = a1.w;
    if (BN == 128) {
#pragma unroll
      for (int q = 0; q < 2; ++q) {
        int lin = tid + q * 256;
        int brow = lin >> 5, bc4 = (lin & 31) << 2;
        *reinterpret_cast<float4*>(&Bs[brow][bc4]) =
            *reinterpret_cast<const float4*>(B + (size_t)(kk + brow) * Ncol + col0 + bc4);
      }
    } else {
      int brow = tid >> 4, bc4 = (tid & 15) << 2;
      *reinterpret_cast<float4*>(&Bs[brow][bc4]) =
          *reinterpret_cast<const float4*>(B + (size_t)(kk + brow) * Ncol + col0 + bc4);
    }
    __syncthreads();
#pragma unroll
    for (int k = 0; k < 16; ++k) {
      float a[8], bv[TN];
      *reinterpret_cast<float4*>(&a[0]) = *reinterpret_cast<const float4*>(&As[k][ty * 8]);
      *reinterpret_cast<float4*>(&a[4]) = *reinterpret_cast<const float4*>(&As[k][ty * 8 + 4]);
#pragma unroll
      for (int q = 0; q < TN / 4; ++q)
        *reinterpret_cast<float4*>(&bv[q * 4]) =
            *reinterpret_cast<const float4*>(&Bs[k][tx * TN + q * 4]);
#pragma unroll
      for (int i = 0; i < 8; ++i)
#pragma unroll
        for (int jn = 0; jn < TN; ++jn)
          acc[i][jn] = fmaf(a[i], bv[jn], acc[i][jn]);
    }
    __syncthreads();
  }
#pragma unroll
  for (int i = 0; i < 8; ++i) {
    int r = row0 + ty * 8 + i;
    if (r < M) {
#pragma unroll
      for (int q = 0; q < TN / 4; ++q)
        *reinterpret_cast<float4*>(C + (size_t)r * Ncol + col0 + tx * TN + q * 4) =
            make_float4(acc[i][q * 4], acc[i][q * 4 + 1], acc[i][q * 4 + 2], acc[i][q * 4 + 3]);
    }
  }
}

// alpha_src/alpha_dst: wave per (node,head); lane = channel (C=64 = wave).
__global__ __launch_bounds__(256) void alpha_kernel(const float* __restrict__ Hf,
                                                    const float* __restrict__ a_src,
                                                    const float* __restrict__ a_dst,
                                                    float* __restrict__ asrc,
                                                    float* __restrict__ adst,
                                                    int N, int H) {
  int wave = threadIdx.x >> 6, lane = threadIdx.x & 63;
  int task = blockIdx.x * 4 + wave;
  if (task >= N * H) return;
  int n = task / H, h = task - n * H;
  float hv = Hf[(size_t)n * (H * 64) + h * 64 + lane];
  float vs = hv * a_src[h * 64 + lane];
  float vd = hv * a_dst[h * 64 + lane];
  for (int off = 32; off; off >>= 1) {
    vs += __shfl_xor(vs, off);
    vd += __shfl_xor(vd, off);
  }
  if (lane == 0) { asrc[task] = vs; adst[task] = vd; }
}

// Online-softmax aggregation: block per dst, wave h owns head h (flash-style
// running max/denominator; acc rescaled on max growth). Single pass over edges.
template <int H, bool ELU>
__global__ __launch_bounds__(H * 64) void seg_aggregate_online(
    const float* __restrict__ hfeat, const int* __restrict__ row_off,
    const int* __restrict__ esrc, const float* __restrict__ asrc,
    const float* __restrict__ adst, const float* __restrict__ bias,
    float* __restrict__ out, int N) {
  __shared__ int s_src[64];
  __shared__ float s_e[64][H];
  __shared__ float s_w[64][H];
  int dst = blockIdx.x;
  int t = threadIdx.x;
  int h = t >> 6, lane = t & 63;
  int r0 = row_off[dst], deg = row_off[dst + 1] - r0;
  int j = t / H, hh = t - j * H;  // staging role
  float adj = adst[dst * H + hh];
  float m = -1e30f, den = 0.f, acc = 0.f;
  for (int base = 0; base < deg; base += 64) {
    int cnt = min(64, deg - base);
    __syncthreads();
    if (j < cnt) {
      int s = esrc[r0 + base + j];
      if (hh == 0) s_src[j] = s;
      float e = asrc[s * H + hh] + adj;
      e = e > 0.f ? e : 0.2f * e;
      s_e[j][hh] = e;
    }
    __syncthreads();
    float ev = (lane < cnt) ? s_e[lane][h] : -1e30f;
    float cm = ev;
    for (int off = 32; off; off >>= 1) cm = fmaxf(cm, __shfl_xor(cm, off));
    float nm = fmaxf(m, cm);
    float scale = expf(m - nm);  // m == -1e30 on first chunk -> 0
    float w = (lane < cnt) ? expf(ev - nm) : 0.f;
    float ws = w;
    for (int off = 32; off; off >>= 1) ws += __shfl_xor(ws, off);
    den = den * scale + ws;
    s_w[lane][h] = w;
    acc *= scale;
    m = nm;
    __syncthreads();
    for (int j2 = 0; j2 < cnt; ++j2)
      acc = fmaf(s_w[j2][h], hfeat[(size_t)s_src[j2] * (H * 64) + t], acc);
  }
  float v = acc / den + bias[t];
  if (ELU) v = v > 0.f ? v : expm1f(v);
  out[(size_t)dst * (H * 64) + t] = v;
}

extern "C" void kernel_launch(void* const* d_in, const int* in_sizes, int n_in,
                              void* d_out, int out_size, void* d_ws, size_t ws_size,
                              hipStream_t stream) {
  const float* x   = (const float*)d_in[0];
  const int*   ei  = (const int*)d_in[1];
  const float* W1  = (const float*)d_in[2];
  const float* as1 = (const float*)d_in[3];
  const float* ad1 = (const float*)d_in[4];
  const float* b1  = (const float*)d_in[5];
  const float* W2  = (const float*)d_in[6];
  const float* as2 = (const float*)d_in[7];
  const float* ad2 = (const float*)d_in[8];
  const float* b2  = (const float*)d_in[9];
  const float* W3  = (const float*)d_in[10];
  const float* as3 = (const float*)d_in[11];
  const float* ad3 = (const float*)d_in[12];
  const float* b3  = (const float*)d_in[13];
  float* out = (float*)d_out;

  const int Fin = 128, H = 4, C = 64, HC = H * C;  // 256
  const int N = in_sizes[0] / Fin;
  const int E = in_sizes[1] / 2;
  const int ET = E + N;
  const int NB = (N + 1023) / 1024;

  // workspace layout
  float* T    = (float*)d_ws;                 // [N, 256] gemm out
  float* F    = T + (size_t)N * HC;           // [N, 256] layer features
  float* asrc = F + (size_t)N * HC;           // [N, H]
  float* adst = asrc + (size_t)N * H;         // [N, H]
  int* deg     = (int*)(adst + (size_t)N * H);
  int* row_off = deg + N;
  int* cursor  = row_off + (N + 1);
  int* bsum    = cursor + N;                  // [NB]
  int* bpre    = bsum + NB;                   // [NB]
  int* esrc    = bpre + NB;                   // [E + N]

  // ---- CSR by destination (graph identical for all 3 layers) ----
  hipMemsetAsync(deg, 0, N * sizeof(int), stream);
  count_kernel<<<(ET + 255) / 256, 256, 0, stream>>>(ei, E, N, deg);
  deg_block_reduce<<<NB, 256, 0, stream>>>(deg, bsum, N);
  small_scan<<<1, 1024, 0, stream>>>(bsum, bpre, NB);
  scan_final<<<NB, 1024, 0, stream>>>(deg, bpre, row_off, cursor, N, ET);
  scatter_kernel<<<(ET + 255) / 256, 256, 0, stream>>>(ei, E, N, cursor, esrc);

  // ---- Layer 1: 128 -> 4x64 (concat) + ELU ----
  gemm_big<128><<<dim3((N + 127) / 128, HC / 128), 256, 0, stream>>>(x, W1, T, N, Fin, HC);
  alpha_kernel<<<(N * H + 3) / 4, 256, 0, stream>>>(T, as1, ad1, asrc, adst, N, H);
  seg_aggregate_online<4, true><<<N, 256, 0, stream>>>(T, row_off, esrc, asrc, adst, b1, F, N);

  // ---- Layer 2: 256 -> 4x64 (concat) + ELU ----
  gemm_big<128><<<dim3((N + 127) / 128, HC / 128), 256, 0, stream>>>(F, W2, T, N, HC, HC);
  alpha_kernel<<<(N * H + 3) / 4, 256, 0, stream>>>(T, as2, ad2, asrc, adst, N, H);
  seg_aggregate_online<4, true><<<N, 256, 0, stream>>>(T, row_off, esrc, asrc, adst, b2, F, N);

  // ---- Layer 3: 256 -> 1x64 (mean over 1 head == identity) ----
  gemm_big<64><<<dim3((N + 127) / 128, C / 64), 256, 0, stream>>>(F, W3, T, N, HC, C);
  alpha_kernel<<<(N * 1 + 3) / 4, 256, 0, stream>>>(T, as3, ad3, asrc, adst, N, 1);
  seg_aggregate_online<1, false><<<N, 64, 0, stream>>>(T, row_off, esrc, asrc, adst, b3, out, N);
}